// Round 7
// baseline (599.543 us; speedup 1.0000x reference)
//
#include <hip/hip_runtime.h>
#include <stdint.h>

// Attention fwd B=4,H=16,N=2048,D=64 fp32.
// Round 7: round-6 barrier-free fragment-direct main loop, but 4 waves/SIMD
// via KV-split. Block = 4 independent waves: w&1 selects Q 64-row half of a
// 128-row tile, w>>1 selects KV half (tiles [0,16) or [16,32)). Fixed-max
// softmax makes partial (unnorm O, l) additive -> one epilogue LDS combine.
// Math identical to verified rounds 2-6: S^T = K*Q^T, pi-permuted Vt frags,
// exp'd scores feed PV from regs, truncation pack.

#define NSEQ 2048
#define DH   64
#define BHN  64

typedef short bf16x8 __attribute__((ext_vector_type(8)));
typedef float f32x4  __attribute__((ext_vector_type(4)));
typedef float f32x16 __attribute__((ext_vector_type(16)));

__device__ __forceinline__ uint16_t f2bf(float x) {
    uint32_t u = __builtin_bit_cast(uint32_t, x);
    return (uint16_t)((u + 0x7fffu + ((u >> 16) & 1u)) >> 16);
}
__device__ __forceinline__ uint32_t pk2(float a, float b) {
    return (uint32_t)f2bf(a) | ((uint32_t)f2bf(b) << 16);
}

// ---------------- prepass: fragment-major K/V gather (unchanged, verified) ----
__global__ __launch_bounds__(256) void prepass(const float* __restrict__ K,
                                               const float* __restrict__ V,
                                               uint16_t* __restrict__ F) {
    __shared__ float T0[64 * 68];
    __shared__ float T1[64 * 68];
    const int b = blockIdx.x, bh = b >> 5, kt = b & 31, t = threadIdx.x;
    const size_t gbase = ((size_t)bh * NSEQ + (size_t)kt * 64) * DH;
    const int n = t >> 2, d0 = (t & 3) * 16;
    #pragma unroll
    for (int i = 0; i < 4; ++i) {
        *(float4*)&T0[n * 68 + d0 + i * 4] = *(const float4*)(K + gbase + n * 64 + d0 + i * 4);
        *(float4*)&T1[n * 68 + d0 + i * 4] = *(const float4*)(V + gbase + n * 64 + d0 + i * 4);
    }
    __syncthreads();
    uint16_t* out = F + (size_t)(bh * 32 + kt) * 8192;
    #pragma unroll
    for (int p = 0; p < 4; ++p) {
        const int e = p * 256 + t, c = e >> 6, l = e & 63;
        const int ll = l & 31, hh = l >> 5;
        float f[8];
        if (c < 8) {            // K A-frag chunk: mtj = c>>2, k2 = c&3
            const int row = (c >> 2) * 32 + ll;
            const int col = hh * 8 + (c & 3) * 16;
            #pragma unroll
            for (int j = 0; j < 8; ++j) f[j] = T0[row * 68 + col + j];
        } else {                // V B-frag chunk: ktg = (c-8)>>1, nd = (c-8)&1
            const int cc = c - 8, ktg = cc >> 1;
            const int d = (cc & 1) * 32 + ll;
            #pragma unroll
            for (int j = 0; j < 8; ++j) {
                const int i = hh * 8 + j;
                const int s = (i & 3) + 8 * ((i >> 2) & 1) + 4 * ((i >> 3) & 1); // pi
                f[j] = T1[(ktg * 16 + s) * 68 + d];
            }
        }
        uint4 o = make_uint4(pk2(f[0], f[1]), pk2(f[2], f[3]),
                             pk2(f[4], f[5]), pk2(f[6], f[7]));
        *(uint4*)(out + (size_t)c * 512 + l * 8) = o;
    }
}

// ---------------- main kernel ----------------
__global__ __launch_bounds__(256, 4) void attn_main(const float* __restrict__ Qg,
                                                    const uint16_t* __restrict__ F,
                                                    float* __restrict__ Og) {
    __shared__ __align__(16) float Obuf[32 * 64 * 4];   // 32 KB: hv=1 partials
    __shared__ float Lpart[2][64];

    const int tid = threadIdx.x;
    const int w = tid >> 6, lane = tid & 63;
    const int l31 = lane & 31, h = lane >> 5;
    const int w01 = w & 1;          // Q half (64 rows)
    const int hv  = w >> 1;         // KV half (16 tiles)

    // XCD-swizzle: blocks idx%8==r serve bh in [r*8, r*8+8) -> 4 MB/XCD-L2
    const int idx = blockIdx.x;
    const int bh = (idx & 7) * 8 + ((idx >> 3) & 7);
    const int qt = idx >> 6;        // [0,16): Q rows qt*128 .. +127

    // Q fragments (B-operand of S^T = K*Q^T), pre-scaled into exp2 domain
    const float qscale = 0.125f * 1.44269504f;
    bf16x8 qf[2][4];
    #pragma unroll
    for (int nt = 0; nt < 2; ++nt) {
        const float* qp = Qg + ((size_t)bh * NSEQ +
                                (size_t)(qt * 128 + w01 * 64 + nt * 32 + l31)) * DH + h * 8;
        #pragma unroll
        for (int k2 = 0; k2 < 4; ++k2) {
            float4 a = *(const float4*)(qp + k2 * 16);
            float4 c = *(const float4*)(qp + k2 * 16 + 4);
            union { uint32_t u[4]; bf16x8 v; } pk;
            pk.u[0] = pk2(a.x * qscale, a.y * qscale);
            pk.u[1] = pk2(a.z * qscale, a.w * qscale);
            pk.u[2] = pk2(c.x * qscale, c.y * qscale);
            pk.u[3] = pk2(c.z * qscale, c.w * qscale);
            qf[nt][k2] = pk.v;
        }
    }

    f32x16 oacc[2][2] = {};
    float lsum[2] = {0.0f, 0.0f};

    const uint16_t* fb = F + ((size_t)bh * 32 + hv * 16) * 8192 + (size_t)lane * 8;

    #pragma unroll 1
    for (int kt = 0; kt < 16; ++kt) {
        uint4 kc[8], vc[8];
        #pragma unroll
        for (int c = 0; c < 8; ++c) kc[c] = *(const uint4*)(fb + (size_t)c * 512);
        #pragma unroll
        for (int c = 0; c < 8; ++c) vc[c] = *(const uint4*)(fb + (size_t)(8 + c) * 512);
        fb += 8192;

        #pragma unroll
        for (int mtj = 0; mtj < 2; ++mtj) {
            #pragma unroll
            for (int nt = 0; nt < 2; ++nt) {
                f32x16 s = {};
                #pragma unroll
                for (int k2 = 0; k2 < 4; ++k2)
                    s = __builtin_amdgcn_mfma_f32_32x32x16_bf16(
                        __builtin_bit_cast(bf16x8, kc[mtj * 4 + k2]), qf[nt][k2], s, 0, 0, 0);
                bf16x8 pf[2];
                float ls = 0.0f;
                #pragma unroll
                for (int ktl = 0; ktl < 2; ++ktl) {
                    union { uint32_t u[4]; bf16x8 v; } pp;
                    #pragma unroll
                    for (int t2 = 0; t2 < 4; ++t2) {
                        float e0 = __builtin_amdgcn_exp2f(s[ktl * 8 + 2 * t2]);
                        float e1 = __builtin_amdgcn_exp2f(s[ktl * 8 + 2 * t2 + 1]);
                        ls += e0 + e1;
                        pp.u[t2] = __builtin_amdgcn_perm(
                            __builtin_bit_cast(uint32_t, e1),
                            __builtin_bit_cast(uint32_t, e0), 0x07060302u);
                    }
                    pf[ktl] = pp.v;
                }
                lsum[nt] += ls;
                #pragma unroll
                for (int nd = 0; nd < 2; ++nd) {
                    oacc[nt][nd] = __builtin_amdgcn_mfma_f32_32x32x16_bf16(
                        pf[0], __builtin_bit_cast(bf16x8, vc[(2 * mtj + 0) * 2 + nd]),
                        oacc[nt][nd], 0, 0, 0);
                    oacc[nt][nd] = __builtin_amdgcn_mfma_f32_32x32x16_bf16(
                        pf[1], __builtin_bit_cast(bf16x8, vc[(2 * mtj + 1) * 2 + nd]),
                        oacc[nt][nd], 0, 0, 0);
                }
            }
        }
    }

    // fold lane halves of l (fixed-max => partials additive across KV halves)
    lsum[0] += __shfl_xor(lsum[0], 32);
    lsum[1] += __shfl_xor(lsum[1], 32);

    // KV-half 1 publishes partial O (b128, conflict-free 16B/lane) and l
    if (hv == 1) {
        #pragma unroll
        for (int nt = 0; nt < 2; ++nt)
            #pragma unroll
            for (int nd = 0; nd < 2; ++nd)
                #pragma unroll
                for (int rg4 = 0; rg4 < 4; ++rg4) {
                    const int slot = w01 * 16 + (nt * 2 + nd) * 4 + rg4;
                    f32x4 v;
                    #pragma unroll
                    for (int j = 0; j < 4; ++j) v[j] = oacc[nt][nd][rg4 * 4 + j];
                    *(f32x4*)&Obuf[(slot * 64 + lane) * 4] = v;
                }
        if (h == 0) {
            Lpart[w01][l31]      = lsum[0];
            Lpart[w01][32 + l31] = lsum[1];
        }
    }
    __syncthreads();
    if (hv == 1) return;

    // KV-half 0 combines, normalizes, stores
    float* Ob = Og + (size_t)bh * NSEQ * DH;
    #pragma unroll
    for (int nt = 0; nt < 2; ++nt) {
        #pragma unroll
        for (int nd = 0; nd < 2; ++nd)
            #pragma unroll
            for (int rg4 = 0; rg4 < 4; ++rg4) {
                const int slot = w01 * 16 + (nt * 2 + nd) * 4 + rg4;
                f32x4 v = *(const f32x4*)&Obuf[(slot * 64 + lane) * 4];
                #pragma unroll
                for (int j = 0; j < 4; ++j) oacc[nt][nd][rg4 * 4 + j] += v[j];
            }
        const float lc = lsum[nt] + Lpart[w01][nt * 32 + l31];
        const float rinv = 1.0f / lc;               // lane l31(+32h) holds row nt*32+l31
        const int rib = __builtin_bit_cast(int, rinv);
        #pragma unroll
        for (int rg = 0; rg < 16; ++rg) {
            const int il = (rg & 3) + 8 * (rg >> 2) + 4 * h;   // C-layout row
            const float inv = __builtin_bit_cast(float,
                __builtin_amdgcn_ds_bpermute(il * 4, rib));
            const int row = qt * 128 + w01 * 64 + nt * 32 + il;
            #pragma unroll
            for (int nd = 0; nd < 2; ++nd)
                Ob[(size_t)row * DH + nd * 32 + l31] = oacc[nt][nd][rg] * inv;
        }
    }
}

// ---------------- fallback (round-1 kernel, if ws too small) ----------------
#define LDS_S 72
#define NWAVE 4
#define BN    64
__global__ __launch_bounds__(256) void attn_fwd_fb(const float* __restrict__ Qg,
                                                   const float* __restrict__ Kg,
                                                   const float* __restrict__ Vg,
                                                   float* __restrict__ Og) {
    __shared__ short KsF[BN * LDS_S];
    __shared__ short VtsF[DH * LDS_S];
    __shared__ short PsF[NWAVE * 16 * LDS_S];
    const int tid = threadIdx.x;
    const int wave = tid >> 6, lane = tid & 63, quad = lane >> 4, l16 = lane & 15;
    const int bh = blockIdx.x >> 5, qtf = blockIdx.x & 31;
    const size_t base = (size_t)bh * NSEQ * DH;
    const float* Qb = Qg + base; const float* Kbf = Kg + base;
    const float* Vb = Vg + base; float* Ob = Og + base;
    const float qscale = 0.125f * 1.44269504f;
    bf16x8 qfrag[2];
    {
        const int qrow = qtf * 64 + wave * 16 + l16;
        const float* qp = Qb + (size_t)qrow * DH + quad * 8;
        #pragma unroll
        for (int c = 0; c < 2; ++c) {
            float4 x = *(const float4*)(qp + 32 * c);
            float4 y = *(const float4*)(qp + 32 * c + 4);
            union { uint16_t u[8]; bf16x8 v; } pk;
            pk.u[0]=f2bf(x.x*qscale); pk.u[1]=f2bf(x.y*qscale);
            pk.u[2]=f2bf(x.z*qscale); pk.u[3]=f2bf(x.w*qscale);
            pk.u[4]=f2bf(y.x*qscale); pk.u[5]=f2bf(y.y*qscale);
            pk.u[6]=f2bf(y.z*qscale); pk.u[7]=f2bf(y.w*qscale);
            qfrag[c] = pk.v;
        }
    }
    f32x4 o[4] = {};
    float m_i[4], l_i[4];
    #pragma unroll
    for (int r = 0; r < 4; ++r) { m_i[r] = -1e30f; l_i[r] = 0.0f; }
    const int kr0 = tid >> 4, kd0 = (tid & 15) * 4;
    const int vp = (tid & 31) * 2, vd0 = (tid >> 5) * 8;
    #pragma unroll 1
    for (int kt = 0; kt < NSEQ / BN; ++kt) {
        __syncthreads();
        {
            const float* kbase = Kbf + (size_t)kt * BN * DH;
            #pragma unroll
            for (int jj = 0; jj < 4; ++jj) {
                const int row = kr0 + jj * 16;
                float4 x = *(const float4*)(kbase + (size_t)row * DH + kd0);
                union { uint16_t u[4]; uint64_t ll; } pk;
                pk.u[0]=f2bf(x.x); pk.u[1]=f2bf(x.y); pk.u[2]=f2bf(x.z); pk.u[3]=f2bf(x.w);
                *(uint64_t*)&KsF[row * LDS_S + kd0] = pk.ll;
            }
        }
        {
            const float* v0 = Vb + (size_t)(kt * BN + vp) * DH + vd0;
            const float* v1 = v0 + DH;
            float4 a0 = *(const float4*)(v0); float4 a1 = *(const float4*)(v0 + 4);
            float4 b0 = *(const float4*)(v1); float4 b1 = *(const float4*)(v1 + 4);
            float av[8] = {a0.x,a0.y,a0.z,a0.w,a1.x,a1.y,a1.z,a1.w};
            float bv[8] = {b0.x,b0.y,b0.z,b0.w,b1.x,b1.y,b1.z,b1.w};
            #pragma unroll
            for (int i = 0; i < 8; ++i)
                *(uint32_t*)&VtsF[(vd0 + i) * LDS_S + vp] = pk2(av[i], bv[i]);
        }
        __syncthreads();
        f32x4 s[4] = {};
        #pragma unroll
        for (int c = 0; c < 2; ++c)
            #pragma unroll
            for (int n = 0; n < 4; ++n) {
                bf16x8 kfr = *(const bf16x8*)&KsF[(n * 16 + l16) * LDS_S + quad * 8 + 32 * c];
                s[n] = __builtin_amdgcn_mfma_f32_16x16x32_bf16(qfrag[c], kfr, s[n], 0, 0, 0);
            }
        float rmax[4];
        #pragma unroll
        for (int r = 0; r < 4; ++r)
            rmax[r] = fmaxf(fmaxf(s[0][r], s[1][r]), fmaxf(s[2][r], s[3][r]));
        #pragma unroll
        for (int off = 1; off < 16; off <<= 1)
            #pragma unroll
            for (int r = 0; r < 4; ++r)
                rmax[r] = fmaxf(rmax[r], __shfl_xor(rmax[r], off, 64));
        float alpha[4], rsum[4];
        #pragma unroll
        for (int r = 0; r < 4; ++r) {
            float mn = fmaxf(m_i[r], rmax[r]);
            alpha[r] = __builtin_amdgcn_exp2f(m_i[r] - mn);
            m_i[r] = mn; rsum[r] = 0.0f;
        }
        #pragma unroll
        for (int n = 0; n < 4; ++n)
            #pragma unroll
            for (int r = 0; r < 4; ++r) {
                float p = __builtin_amdgcn_exp2f(s[n][r] - m_i[r]);
                rsum[r] += p;
                PsF[(wave * 16 + quad * 4 + r) * LDS_S + n * 16 + l16] = (short)f2bf(p);
            }
        #pragma unroll
        for (int off = 1; off < 16; off <<= 1)
            #pragma unroll
            for (int r = 0; r < 4; ++r)
                rsum[r] += __shfl_xor(rsum[r], off, 64);
        #pragma unroll
        for (int r = 0; r < 4; ++r) l_i[r] = l_i[r] * alpha[r] + rsum[r];
        #pragma unroll
        for (int n = 0; n < 4; ++n)
            #pragma unroll
            for (int r = 0; r < 4; ++r) o[n][r] *= alpha[r];
        #pragma unroll
        for (int c = 0; c < 2; ++c) {
            bf16x8 pfr = *(const bf16x8*)&PsF[(wave * 16 + l16) * LDS_S + quad * 8 + 32 * c];
            #pragma unroll
            for (int n = 0; n < 4; ++n) {
                bf16x8 vfr = *(const bf16x8*)&VtsF[(n * 16 + l16) * LDS_S + quad * 8 + 32 * c];
                o[n] = __builtin_amdgcn_mfma_f32_16x16x32_bf16(pfr, vfr, o[n], 0, 0, 0);
            }
        }
    }
    float inv[4];
    #pragma unroll
    for (int r = 0; r < 4; ++r) inv[r] = 1.0f / l_i[r];
    const int orow0 = qtf * 64 + wave * 16 + quad * 4;
    #pragma unroll
    for (int n = 0; n < 4; ++n)
        #pragma unroll
        for (int r = 0; r < 4; ++r)
            Ob[(size_t)(orow0 + r) * DH + n * 16 + l16] = o[n][r] * inv[r];
}

extern "C" void kernel_launch(void* const* d_in, const int* in_sizes, int n_in,
                              void* d_out, int out_size, void* d_ws, size_t ws_size,
                              hipStream_t stream) {
    (void)in_sizes; (void)n_in; (void)out_size;
    const float* q = (const float*)d_in[0];
    const float* k = (const float*)d_in[1];
    const float* v = (const float*)d_in[2];
    float* out = (float*)d_out;
    const size_t need = (size_t)BHN * 32 * 16384;   // 33.55 MB fragment buffer
    if (ws_size >= need) {
        uint16_t* fbuf = (uint16_t*)d_ws;
        prepass<<<dim3(BHN * 32), dim3(256), 0, stream>>>(k, v, fbuf);
        attn_main<<<dim3(1024), dim3(256), 0, stream>>>(q, fbuf, out);
    } else {
        attn_fwd_fb<<<dim3(BHN * 32), dim3(256), 0, stream>>>(q, k, v, out);
    }
}

// Round 8
// 265.752 us; speedup vs baseline: 2.2560x; 2.2560x over previous
//
#include <hip/hip_runtime.h>
#include <stdint.h>

// Attention fwd B=4,H=16,N=2048,D=64 fp32.
// Round 8: round-6 kernel (proven 85.5us) + occupancy push to 3 waves/SIMD.
// Calibrated model: waves/SIMD = floor(512 / (VGPR+AGPR)). Round 6 was
// 112V + 64A = 176 -> 2 waves. Here: __launch_bounds__(64,3) caps total at
// 170 (VGPR cap 106 given the 64-AGPR accumulator), and V-fragment loads are
// split per mtj half to cut peak staging pressure so the allocator gets
// under the cap WITHOUT in-loop spills (round-7 disaster = forcing 176->128).
// Math identical to verified rounds 2-7: fragment-major ws, S^T = K*Q^T,
// pi-permuted Vt frags, exp'd scores feed PV from regs, truncation pack.

#define NSEQ 2048
#define DH   64
#define BHN  64
#define NIT  32

typedef short bf16x8 __attribute__((ext_vector_type(8)));
typedef float f32x4  __attribute__((ext_vector_type(4)));
typedef float f32x16 __attribute__((ext_vector_type(16)));

__device__ __forceinline__ uint16_t f2bf(float x) {
    uint32_t u = __builtin_bit_cast(uint32_t, x);
    return (uint16_t)((u + 0x7fffu + ((u >> 16) & 1u)) >> 16);
}
__device__ __forceinline__ uint32_t pk2(float a, float b) {
    return (uint32_t)f2bf(a) | ((uint32_t)f2bf(b) << 16);
}

// ---------------- prepass: fragment-major K/V gather (unchanged, verified) ----
__global__ __launch_bounds__(256) void prepass(const float* __restrict__ K,
                                               const float* __restrict__ V,
                                               uint16_t* __restrict__ F) {
    __shared__ float T0[64 * 68];
    __shared__ float T1[64 * 68];
    const int b = blockIdx.x, bh = b >> 5, kt = b & 31, t = threadIdx.x;
    const size_t gbase = ((size_t)bh * NSEQ + (size_t)kt * 64) * DH;
    const int n = t >> 2, d0 = (t & 3) * 16;
    #pragma unroll
    for (int i = 0; i < 4; ++i) {
        *(float4*)&T0[n * 68 + d0 + i * 4] = *(const float4*)(K + gbase + n * 64 + d0 + i * 4);
        *(float4*)&T1[n * 68 + d0 + i * 4] = *(const float4*)(V + gbase + n * 64 + d0 + i * 4);
    }
    __syncthreads();
    uint16_t* out = F + (size_t)(bh * 32 + kt) * 8192;
    #pragma unroll
    for (int p = 0; p < 4; ++p) {
        const int e = p * 256 + t, c = e >> 6, l = e & 63;
        const int ll = l & 31, hh = l >> 5;
        float f[8];
        if (c < 8) {            // K A-frag chunk: mtj = c>>2, k2 = c&3
            const int row = (c >> 2) * 32 + ll;
            const int col = hh * 8 + (c & 3) * 16;
            #pragma unroll
            for (int j = 0; j < 8; ++j) f[j] = T0[row * 68 + col + j];
        } else {                // V B-frag chunk: ktg = (c-8)>>1, nd = (c-8)&1
            const int cc = c - 8, ktg = cc >> 1;
            const int d = (cc & 1) * 32 + ll;
            #pragma unroll
            for (int j = 0; j < 8; ++j) {
                const int i = hh * 8 + j;
                const int s = (i & 3) + 8 * ((i >> 2) & 1) + 4 * ((i >> 3) & 1); // pi
                f[j] = T1[(ktg * 16 + s) * 68 + d];
            }
        }
        uint4 o = make_uint4(pk2(f[0], f[1]), pk2(f[2], f[3]),
                             pk2(f[4], f[5]), pk2(f[6], f[7]));
        *(uint4*)(out + (size_t)c * 512 + l * 8) = o;
    }
}

// ---------------- main kernel: 1 wave per 64 Q rows, no LDS, no barriers ----
__global__ __launch_bounds__(64, 3) void attn_main(const float* __restrict__ Qg,
                                                   const uint16_t* __restrict__ F,
                                                   float* __restrict__ Og) {
    const int lane = threadIdx.x;
    const int l31 = lane & 31, h = lane >> 5;
    const int idx = blockIdx.x;
    const int bh = (idx & 7) * 8 + ((idx >> 3) & 7);   // XCD swizzle
    const int qt = idx >> 6;

    const float qscale = 0.125f * 1.44269504f;
    bf16x8 qf[2][4];
    #pragma unroll
    for (int nt = 0; nt < 2; ++nt) {
        const float* qp = Qg + ((size_t)bh * NSEQ +
                                (size_t)(qt * 64 + nt * 32 + l31)) * DH + h * 8;
        #pragma unroll
        for (int k2 = 0; k2 < 4; ++k2) {
            float4 a = *(const float4*)(qp + k2 * 16);
            float4 c = *(const float4*)(qp + k2 * 16 + 4);
            union { uint32_t u[4]; bf16x8 v; } pk;
            pk.u[0] = pk2(a.x * qscale, a.y * qscale);
            pk.u[1] = pk2(a.z * qscale, a.w * qscale);
            pk.u[2] = pk2(c.x * qscale, c.y * qscale);
            pk.u[3] = pk2(c.z * qscale, c.w * qscale);
            qf[nt][k2] = pk.v;
        }
    }

    f32x16 oacc[2][2] = {};
    float lsum[2] = {0.0f, 0.0f};

    const uint16_t* fb = F + (size_t)bh * 32 * 8192 + (size_t)lane * 8;

    #pragma unroll 1
    for (int kt = 0; kt < NIT; ++kt) {
        // K frags (all 8) + V frags for mtj=0 half (chunks 8..11)
        uint4 kc[8], vca[4], vcb[4];
        #pragma unroll
        for (int c = 0; c < 8; ++c) kc[c] = *(const uint4*)(fb + (size_t)c * 512);
        #pragma unroll
        for (int c = 0; c < 4; ++c) vca[c] = *(const uint4*)(fb + (size_t)(8 + c) * 512);

        #pragma unroll
        for (int mtj = 0; mtj < 2; ++mtj) {
            const uint4* vh = (mtj == 0) ? vca : vcb;
            #pragma unroll
            for (int nt = 0; nt < 2; ++nt) {
                f32x16 s = {};
                #pragma unroll
                for (int k2 = 0; k2 < 4; ++k2)
                    s = __builtin_amdgcn_mfma_f32_32x32x16_bf16(
                        __builtin_bit_cast(bf16x8, kc[mtj * 4 + k2]), qf[nt][k2], s, 0, 0, 0);
                bf16x8 pf[2];
                float ls = 0.0f;
                #pragma unroll
                for (int ktl = 0; ktl < 2; ++ktl) {
                    union { uint32_t u[4]; bf16x8 v; } pp;
                    #pragma unroll
                    for (int t2 = 0; t2 < 4; ++t2) {
                        float e0 = __builtin_amdgcn_exp2f(s[ktl * 8 + 2 * t2]);
                        float e1 = __builtin_amdgcn_exp2f(s[ktl * 8 + 2 * t2 + 1]);
                        ls += e0 + e1;
                        pp.u[t2] = __builtin_amdgcn_perm(
                            __builtin_bit_cast(uint32_t, e1),
                            __builtin_bit_cast(uint32_t, e0), 0x07060302u);
                    }
                    pf[ktl] = pp.v;
                }
                lsum[nt] += ls;
                #pragma unroll
                for (int nd = 0; nd < 2; ++nd) {
                    oacc[nt][nd] = __builtin_amdgcn_mfma_f32_32x32x16_bf16(
                        pf[0], __builtin_bit_cast(bf16x8, vh[0 * 2 + nd]),
                        oacc[nt][nd], 0, 0, 0);
                    oacc[nt][nd] = __builtin_amdgcn_mfma_f32_32x32x16_bf16(
                        pf[1], __builtin_bit_cast(bf16x8, vh[1 * 2 + nd]),
                        oacc[nt][nd], 0, 0, 0);
                }
            }
            // load V frags for mtj=1 half (chunks 12..15) after mtj=0 compute
            // is issued: latency hidden behind exp2+PV, peak staging regs -16.
            if (mtj == 0) {
                #pragma unroll
                for (int c = 0; c < 4; ++c)
                    vcb[c] = *(const uint4*)(fb + (size_t)(12 + c) * 512);
            }
        }
        fb += 8192;
    }

    // epilogue: fold lane halves; distribute 1/l via ds_bpermute
    float* Ob = Og + (size_t)bh * NSEQ * DH;
    #pragma unroll
    for (int nt = 0; nt < 2; ++nt) {
        float lt = lsum[nt] + __shfl_xor(lsum[nt], 32);
        float rinv = 1.0f / lt;
        int rib = __builtin_bit_cast(int, rinv);
        #pragma unroll
        for (int rg = 0; rg < 16; ++rg) {
            const int il = (rg & 3) + 8 * (rg >> 2) + 4 * h;
            const float inv = __builtin_bit_cast(float,
                __builtin_amdgcn_ds_bpermute(il * 4, rib));
            const int row = qt * 64 + nt * 32 + il;
            #pragma unroll
            for (int nd = 0; nd < 2; ++nd)
                Ob[(size_t)row * DH + nd * 32 + l31] = oacc[nt][nd][rg] * inv;
        }
    }
}

// ---------------- fallback (round-1 kernel, if ws too small) ----------------
#define LDS_S 72
#define NWAVE 4
#define BN    64
__global__ __launch_bounds__(256) void attn_fwd_fb(const float* __restrict__ Qg,
                                                   const float* __restrict__ Kg,
                                                   const float* __restrict__ Vg,
                                                   float* __restrict__ Og) {
    __shared__ short KsF[BN * LDS_S];
    __shared__ short VtsF[DH * LDS_S];
    __shared__ short PsF[NWAVE * 16 * LDS_S];
    const int tid = threadIdx.x;
    const int wave = tid >> 6, lane = tid & 63, quad = lane >> 4, l16 = lane & 15;
    const int bh = blockIdx.x >> 5, qtf = blockIdx.x & 31;
    const size_t base = (size_t)bh * NSEQ * DH;
    const float* Qb = Qg + base; const float* Kbf = Kg + base;
    const float* Vb = Vg + base; float* Ob = Og + base;
    const float qscale = 0.125f * 1.44269504f;
    bf16x8 qfrag[2];
    {
        const int qrow = qtf * 64 + wave * 16 + l16;
        const float* qp = Qb + (size_t)qrow * DH + quad * 8;
        #pragma unroll
        for (int c = 0; c < 2; ++c) {
            float4 x = *(const float4*)(qp + 32 * c);
            float4 y = *(const float4*)(qp + 32 * c + 4);
            union { uint16_t u[8]; bf16x8 v; } pk;
            pk.u[0]=f2bf(x.x*qscale); pk.u[1]=f2bf(x.y*qscale);
            pk.u[2]=f2bf(x.z*qscale); pk.u[3]=f2bf(x.w*qscale);
            pk.u[4]=f2bf(y.x*qscale); pk.u[5]=f2bf(y.y*qscale);
            pk.u[6]=f2bf(y.z*qscale); pk.u[7]=f2bf(y.w*qscale);
            qfrag[c] = pk.v;
        }
    }
    f32x4 o[4] = {};
    float m_i[4], l_i[4];
    #pragma unroll
    for (int r = 0; r < 4; ++r) { m_i[r] = -1e30f; l_i[r] = 0.0f; }
    const int kr0 = tid >> 4, kd0 = (tid & 15) * 4;
    const int vp = (tid & 31) * 2, vd0 = (tid >> 5) * 8;
    #pragma unroll 1
    for (int kt = 0; kt < NSEQ / BN; ++kt) {
        __syncthreads();
        {
            const float* kbase = Kbf + (size_t)kt * BN * DH;
            #pragma unroll
            for (int jj = 0; jj < 4; ++jj) {
                const int row = kr0 + jj * 16;
                float4 x = *(const float4*)(kbase + (size_t)row * DH + kd0);
                union { uint16_t u[4]; uint64_t ll; } pk;
                pk.u[0]=f2bf(x.x); pk.u[1]=f2bf(x.y); pk.u[2]=f2bf(x.z); pk.u[3]=f2bf(x.w);
                *(uint64_t*)&KsF[row * LDS_S + kd0] = pk.ll;
            }
        }
        {
            const float* v0 = Vb + (size_t)(kt * BN + vp) * DH + vd0;
            const float* v1 = v0 + DH;
            float4 a0 = *(const float4*)(v0); float4 a1 = *(const float4*)(v0 + 4);
            float4 b0 = *(const float4*)(v1); float4 b1 = *(const float4*)(v1 + 4);
            float av[8] = {a0.x,a0.y,a0.z,a0.w,a1.x,a1.y,a1.z,a1.w};
            float bv[8] = {b0.x,b0.y,b0.z,b0.w,b1.x,b1.y,b1.z,b1.w};
            #pragma unroll
            for (int i = 0; i < 8; ++i)
                *(uint32_t*)&VtsF[(vd0 + i) * LDS_S + vp] = pk2(av[i], bv[i]);
        }
        __syncthreads();
        f32x4 s[4] = {};
        #pragma unroll
        for (int c = 0; c < 2; ++c)
            #pragma unroll
            for (int n = 0; n < 4; ++n) {
                bf16x8 kfr = *(const bf16x8*)&KsF[(n * 16 + l16) * LDS_S + quad * 8 + 32 * c];
                s[n] = __builtin_amdgcn_mfma_f32_16x16x32_bf16(qfrag[c], kfr, s[n], 0, 0, 0);
            }
        float rmax[4];
        #pragma unroll
        for (int r = 0; r < 4; ++r)
            rmax[r] = fmaxf(fmaxf(s[0][r], s[1][r]), fmaxf(s[2][r], s[3][r]));
        #pragma unroll
        for (int off = 1; off < 16; off <<= 1)
            #pragma unroll
            for (int r = 0; r < 4; ++r)
                rmax[r] = fmaxf(rmax[r], __shfl_xor(rmax[r], off, 64));
        float alpha[4], rsum[4];
        #pragma unroll
        for (int r = 0; r < 4; ++r) {
            float mn = fmaxf(m_i[r], rmax[r]);
            alpha[r] = __builtin_amdgcn_exp2f(m_i[r] - mn);
            m_i[r] = mn; rsum[r] = 0.0f;
        }
        #pragma unroll
        for (int n = 0; n < 4; ++n)
            #pragma unroll
            for (int r = 0; r < 4; ++r) {
                float p = __builtin_amdgcn_exp2f(s[n][r] - m_i[r]);
                rsum[r] += p;
                PsF[(wave * 16 + quad * 4 + r) * LDS_S + n * 16 + l16] = (short)f2bf(p);
            }
        #pragma unroll
        for (int off = 1; off < 16; off <<= 1)
            #pragma unroll
            for (int r = 0; r < 4; ++r)
                rsum[r] += __shfl_xor(rsum[r], off, 64);
        #pragma unroll
        for (int r = 0; r < 4; ++r) l_i[r] = l_i[r] * alpha[r] + rsum[r];
        #pragma unroll
        for (int n = 0; n < 4; ++n)
            #pragma unroll
            for (int r = 0; r < 4; ++r) o[n][r] *= alpha[r];
        #pragma unroll
        for (int c = 0; c < 2; ++c) {
            bf16x8 pfr = *(const bf16x8*)&PsF[(wave * 16 + l16) * LDS_S + quad * 8 + 32 * c];
            #pragma unroll
            for (int n = 0; n < 4; ++n) {
                bf16x8 vfr = *(const bf16x8*)&VtsF[(n * 16 + l16) * LDS_S + quad * 8 + 32 * c];
                o[n] = __builtin_amdgcn_mfma_f32_16x16x32_bf16(pfr, vfr, o[n], 0, 0, 0);
            }
        }
    }
    float inv[4];
    #pragma unroll
    for (int r = 0; r < 4; ++r) inv[r] = 1.0f / l_i[r];
    const int orow0 = qtf * 64 + wave * 16 + quad * 4;
    #pragma unroll
    for (int n = 0; n < 4; ++n)
        #pragma unroll
        for (int r = 0; r < 4; ++r)
            Ob[(size_t)(orow0 + r) * DH + n * 16 + l16] = o[n][r] * inv[r];
}

extern "C" void kernel_launch(void* const* d_in, const int* in_sizes, int n_in,
                              void* d_out, int out_size, void* d_ws, size_t ws_size,
                              hipStream_t stream) {
    (void)in_sizes; (void)n_in; (void)out_size;
    const float* q = (const float*)d_in[0];
    const float* k = (const float*)d_in[1];
    const float* v = (const float*)d_in[2];
    float* out = (float*)d_out;
    const size_t need = (size_t)BHN * 32 * 16384;   // 33.55 MB fragment buffer
    if (ws_size >= need) {
        uint16_t* fbuf = (uint16_t*)d_ws;
        prepass<<<dim3(BHN * 32), dim3(256), 0, stream>>>(k, v, fbuf);
        attn_main<<<dim3(2048), dim3(64), 0, stream>>>(q, fbuf, out);
    } else {
        attn_fwd_fb<<<dim3(BHN * 32), dim3(256), 0, stream>>>(q, k, v, out);
    }
}